// Round 13
// baseline (2194.108 us; speedup 1.0000x reference)
//
#include <hip/hip_runtime.h>

typedef unsigned int u32;

constexpr int BATCH = 8;
constexpr int GH = 32, GW = 64;
constexpr int FH = 128, FW = 512;
constexpr int NFFT = 1024;
constexpr int HOP = 256;
constexpr int NFREQ = 513;
constexpr int NW = 512;                       // frames per batch
constexpr int SIGLEN = HOP * (NW - 1);        // 130816
constexpr int TOTAL_LEN = NFFT + HOP*(NW-1);  // 131840
constexpr int NITER = 32;
constexpr int NSAMP = 131072;
constexpr int NMAG = BATCH * NW * NFREQ;      // 2101248

// LDS index padding (9/8 stride)
#define SL(i) ((i) + ((i) >> 3))
constexpr int LDSN = 512 + 64;                // 576 slots

__device__ __forceinline__ void wbar() { __builtin_amdgcn_wave_barrier(); }

// ---------------- Threefry-2x32-20, partitionable path (key = (0,1)) ----------------
__device__ __forceinline__ void tf_round(u32 &x0, u32 &x1, int r) {
  x0 += x1;
  x1 = (x1 << r) | (x1 >> (32 - r));
  x1 ^= x0;
}

__device__ __forceinline__ void threefry2(u32 c0, u32 c1, u32 &o0, u32 &o1) {
  const u32 k0 = 0u, k1 = 1u;
  const u32 k2 = 0x1BD11BDAu ^ k0 ^ k1;
  u32 x0 = c0 + k0, x1 = c1 + k1;
  tf_round(x0, x1, 13); tf_round(x0, x1, 15); tf_round(x0, x1, 26); tf_round(x0, x1, 6);
  x0 += k1; x1 += k2 + 1u;
  tf_round(x0, x1, 17); tf_round(x0, x1, 29); tf_round(x0, x1, 16); tf_round(x0, x1, 24);
  x0 += k2; x1 += k0 + 2u;
  tf_round(x0, x1, 13); tf_round(x0, x1, 15); tf_round(x0, x1, 26); tf_round(x0, x1, 6);
  x0 += k0; x1 += k1 + 3u;
  tf_round(x0, x1, 17); tf_round(x0, x1, 29); tf_round(x0, x1, 16); tf_round(x0, x1, 24);
  x0 += k1; x1 += k2 + 4u;
  tf_round(x0, x1, 13); tf_round(x0, x1, 15); tf_round(x0, x1, 26); tf_round(x0, x1, 6);
  x0 += k2; x1 += k0 + 5u;
  o0 = x0; o1 = x1;
}

// ---------------- init: win f32, twiddle tables f64, wsq f32, tprev=0 ----------------
__global__ __launch_bounds__(256) void k_init(float* __restrict__ win,
                                              double2* __restrict__ tw512, double2* __restrict__ twh,
                                              float* __restrict__ wsq,
                                              float2* __restrict__ tprev)
{
  int idx = blockIdx.x * 256 + threadIdx.x;
  int stride = gridDim.x * 256;
  const double PI2 = 6.283185307179586476925286766559;
  for (int t = idx; t < NFFT; t += stride)
    win[t] = (float)(0.5 * (1.0 - cos(PI2 * (double)t / 1024.0)));  // _WIN f32
  for (int k = idx; k < 512; k += stride) {
    double th = -PI2 * (double)k / 512.0;
    double2 v; v.x = cos(th); v.y = sin(th);
    tw512[k] = v;                                     // e^{-2pi i k/512}
    double th2 = -PI2 * (double)k / 1024.0;
    double2 v2; v2.x = cos(th2); v2.y = sin(th2);
    twh[k] = v2;                                      // e^{-2pi i k/1024}
  }
  for (int j = idx; j < TOTAL_LEN; j += stride) {
    int gmax = j >> 8; if (gmax > NW - 1) gmax = NW - 1;
    int gmin = (j >= NFFT) ? ((j - (NFFT - 1) + 255) >> 8) : 0;
    float acc = 0.f;                       // f32 scatter-add, ascending frame order
    for (int g = gmin; g <= gmax; ++g) {
      float w = (float)(0.5 * (1.0 - cos(PI2 * (double)(j - (g << 8)) / 1024.0)));
      acc = __fadd_rn(acc, __fmul_rn(w, w));
    }
    wsq[j] = acc;
  }
  for (int i = idx; i < NMAG; i += stride)
    tprev[i] = make_float2(0.f, 0.f);
}

// ---------------- jax.image.resize bilinear, f32 weights WITH sum-normalization ----------------
__device__ __forceinline__ void lin_taps(float sf, int in, int &i0, int &i1, float &w0, float &w1)
{
  if (sf <= 0.0f)                  { i0 = 0;      i1 = 0;      w0 = 1.0f; w1 = 0.0f; return; }
  if (sf >= (float)(in - 1))       { i0 = in - 1; i1 = in - 1; w0 = 1.0f; w1 = 0.0f; return; }
  i0 = (int)sf; i1 = i0 + 1;
  float x0 = __fsub_rn(sf, (float)i0);   // exact
  float a0 = __fsub_rn(1.0f, x0);
  float S  = __fadd_rn(a0, x0);          // total_weight_sum = 1 +/- 2^-24
  w0 = __fdiv_rn(a0, S);                 // normalized (jax divides by the sum)
  w1 = __fdiv_rn(x0, S);
}

__device__ __forceinline__ float sf_H1(int H) {  // 32 -> 128
  return __fadd_rn(__fmul_rn(__fadd_rn((float)H, 0.5f), 0.25f), -0.5f);
}
__device__ __forceinline__ float sf_W1(int W) {  // 64 -> 512
  return __fadd_rn(__fmul_rn(__fadd_rn((float)W, 0.5f), 0.125f), -0.5f);
}
__device__ __forceinline__ float sf_H2(int K) {  // 128 -> 513, f32 inv_scale
  const float inv32 = (float)(1.0 / 4.0078125);  // f32(128/513)
  return __fadd_rn(__fmul_rn(__fadd_rn((float)K, 0.5f), inv32), -0.5f);
}

__device__ __forceinline__ float fs_at(const float* __restrict__ pb, int H, int W)
{
  int r0, r1; float u0, u1;
  lin_taps(sf_H1(H), GH, r0, r1, u0, u1);
  int c0, c1; float v0, v1;
  lin_taps(sf_W1(W), GW, c0, c1, v0, v1);
  float t0 = __fmaf_rn(u1, pb[r1 * GW + c0], __fmul_rn(u0, pb[r0 * GW + c0]));
  float t1 = __fmaf_rn(u1, pb[r1 * GW + c1], __fmul_rn(u0, pb[r0 * GW + c1]));
  return __fmaf_rn(v1, t1, __fmul_rn(v0, t0));
}

__global__ __launch_bounds__(256) void k_fullspec(const float* __restrict__ p, float* __restrict__ fs)
{
  int idx = blockIdx.x * 256 + threadIdx.x;
  if (idx >= BATCH * FH * FW) return;
  int b = idx >> 16;
  int h = (idx >> 9) & (FH - 1);
  int w = idx & (FW - 1);
  fs[idx] = fs_at(p + b * (GH * GW), h, w);
}

__global__ __launch_bounds__(256) void k_mag(const float* __restrict__ p, float* __restrict__ mag)
{
  int idx = blockIdx.x * 256 + threadIdx.x;
  if (idx >= NMAG) return;
  int b = idx / (NW * NFREQ);
  int rem = idx - b * (NW * NFREQ);
  int f = rem / NFREQ;
  int k = rem - f * NFREQ;
  const float* pb = p + b * (GH * GW);
  int h0, h1; float wa, wb;
  lin_taps(sf_H2(k), FH, h0, h1, wa, wb);
  float fs0 = fs_at(pb, h0, f);
  float fs1 = fs_at(pb, h1, f);
  float P0 = __fmul_rn(__fmul_rn(fs0, fs0), 100.0f);
  float P1 = __fmul_rn(__fmul_rn(fs1, fs1), 100.0f);
  float lin = __fmaf_rn(wb, P1, __fmul_rn(wa, P0));
  mag[idx] = __fsqrt_rn(fmaxf(lin, 0.0f));
}

__global__ __launch_bounds__(256) void k_phase(float2* __restrict__ ang)
{
  int idx = blockIdx.x * 256 + threadIdx.x;
  if (idx >= NMAG) return;
  int b = idx / (NW * NFREQ);
  int rem = idx - b * (NW * NFREQ);
  int f = rem / NFREQ;
  int k = rem - f * NFREQ;
  u32 cnt = (u32)(b * (NFREQ * NW) + k * NW + f);  // flat index in (B,513,512) C-order
  u32 w0, w1;
  threefry2(0u, cnt, w0, w1);
  u32 bits = w0 ^ w1;
  float u = __uint_as_float((bits >> 9) | 0x3f800000u) - 1.0f;
  float th = __fmul_rn((float)6.283185307179586, u);
  double thd = (double)th;
  ang[idx] = make_float2((float)cos(thd), (float)sin(thd));
}

// ---------------- 8-point butterfly in registers (R10-verified vs DFT-8, fwd+inv) ----------------
template<bool INV>
__device__ __forceinline__ void bfly8(const double2 x[8], double2 y[8])
{
  const double C = 0.70710678118654752440084436210485;  // sqrt(2)/2
  double2 a0, a1, a2, a3, b0, b1, b2, b3;
  a0.x = x[0].x + x[4].x; a0.y = x[0].y + x[4].y; b0.x = x[0].x - x[4].x; b0.y = x[0].y - x[4].y;
  a1.x = x[1].x + x[5].x; a1.y = x[1].y + x[5].y; b1.x = x[1].x - x[5].x; b1.y = x[1].y - x[5].y;
  a2.x = x[2].x + x[6].x; a2.y = x[2].y + x[6].y; b2.x = x[2].x - x[6].x; b2.y = x[2].y - x[6].y;
  a3.x = x[3].x + x[7].x; a3.y = x[3].y + x[7].y; b3.x = x[3].x - x[7].x; b3.y = x[3].y - x[7].y;
  double e0x = a0.x + a2.x, e0y = a0.y + a2.y;
  double e1x = a0.x - a2.x, e1y = a0.y - a2.y;
  double e2x = a1.x + a3.x, e2y = a1.y + a3.y;
  double e3x = a1.x - a3.x, e3y = a1.y - a3.y;
  y[0].x = e0x + e2x; y[0].y = e0y + e2y;
  y[4].x = e0x - e2x; y[4].y = e0y - e2y;
  if (!INV) { y[2].x = e1x + e3y; y[2].y = e1y - e3x; y[6].x = e1x - e3y; y[6].y = e1y + e3x; }
  else      { y[2].x = e1x - e3y; y[2].y = e1y + e3x; y[6].x = e1x + e3y; y[6].y = e1y - e3x; }
  double2 t0 = b0, t1, t2, t3;
  if (!INV) {
    t1.x = C * (b1.x + b1.y);  t1.y = C * (b1.y - b1.x);    // *(c,-c)
    t2.x = b2.y;               t2.y = -b2.x;                // *(-i)
    t3.x = C * (b3.y - b3.x);  t3.y = -C * (b3.x + b3.y);   // *(-c,-c)
  } else {
    t1.x = C * (b1.x - b1.y);  t1.y = C * (b1.y + b1.x);    // *(c,c)
    t2.x = -b2.y;              t2.y = b2.x;                 // *(+i)
    t3.x = -C * (b3.x + b3.y); t3.y = C * (b3.x - b3.y);    // *(-c,c)
  }
  double o0x = t0.x + t2.x, o0y = t0.y + t2.y;
  double o1x = t0.x - t2.x, o1y = t0.y - t2.y;
  double o2x = t1.x + t3.x, o2y = t1.y + t3.y;
  double o3x = t1.x - t3.x, o3y = t1.y - t3.y;
  y[1].x = o0x + o2x; y[1].y = o0y + o2y;
  y[5].x = o0x - o2x; y[5].y = o0y - o2y;
  if (!INV) { y[3].x = o1x + o3y; y[3].y = o1y - o3x; y[7].x = o1x - o3y; y[7].y = o1y + o3x; }
  else      { y[3].x = o1x - o3y; y[3].y = o1y + o3x; y[7].x = o1x + o3y; y[7].y = o1y - o3x; }
}

// ---------------- 512-pt complex FFT: 3 radix-8 Stockham stages, WAVE-SYNCHRONOUS ----------------
// 64 lanes (l = 0..63), A is this wave's PRIVATE padded LDS region. DS ops from one wave
// complete in order -> no s_barrier needed; wbar() is a compiler scheduling fence only.
// Math identical to R10's fft512r8 (bit-verified). Result in A, natural order.
template<bool INV>
__device__ __forceinline__ void fft512r8w(double2* __restrict__ A,
                                          const double2* __restrict__ tw512, int l)
{
  #pragma unroll
  for (int s = 0; s < 3; ++s) {
    const int sh = 3 * s;
    const int L = 1 << sh;           // 8^s
    const int m = 64 >> sh;
    int p = l >> sh;
    int q = l & (L - 1);
    double2 x[8];
    #pragma unroll
    for (int j = 0; j < 8; ++j)
      x[j] = A[SL(q + (p + j * m) * L)];
    wbar();
    double2 y[8];
    bfly8<INV>(x, y);
    int base = p << sh;              // p * 8^s
    int ob = q + (p << (sh + 3));    // q + 8p*L
    A[SL(ob)] = y[0];
    #pragma unroll
    for (int j = 1; j < 8; ++j) {
      double2 w = tw512[j * base];
      double wy = INV ? -w.y : w.y;
      double2 o;
      o.x = y[j].x * w.x - y[j].y * wy;
      o.y = y[j].x * wy + y[j].y * w.x;
      A[SL(ob + j * L)] = o;
    }
    wbar();
  }
}

// ---------------- initial ISTFT: radix-4 single-buffer (R12-proven), 128 threads ----------------
template<bool INV>
__device__ __forceinline__ void fft512d1(double2* __restrict__ A,
                                         const double2* __restrict__ tw512, int t)
{
  #pragma unroll
  for (int s = 0; s < 4; ++s) {
    const int L = 1 << (2 * s);
    const int m = 128 >> (2 * s);
    int p = t >> (2 * s);
    int q = t & (L - 1);
    double2 x0 = A[SL(q + (p)         * L)];
    double2 x1 = A[SL(q + (p + m)     * L)];
    double2 x2 = A[SL(q + (p + 2 * m) * L)];
    double2 x3 = A[SL(q + (p + 3 * m) * L)];
    __syncthreads();
    double t0x = x0.x + x2.x, t0y = x0.y + x2.y;
    double t1x = x0.x - x2.x, t1y = x0.y - x2.y;
    double t2x = x1.x + x3.x, t2y = x1.y + x3.y;
    double t3x = x1.x - x3.x, t3y = x1.y - x3.y;
    double y0x = t0x + t2x, y0y = t0y + t2y;
    double y2x = t0x - t2x, y2y = t0y - t2y;
    double y1x, y1y, y3x, y3y;
    if (INV) { y1x = t1x - t3y; y1y = t1y + t3x; y3x = t1x + t3y; y3y = t1y - t3x; }
    else     { y1x = t1x + t3y; y1y = t1y - t3x; y3x = t1x - t3y; y3y = t1y + t3x; }
    int base = p << (2 * s);
    double2 w1 = tw512[base];
    double2 w2 = tw512[2 * base];
    double2 w3 = tw512[3 * base];
    double w1y = INV ? -w1.y : w1.y;
    double w2y = INV ? -w2.y : w2.y;
    double w3y = INV ? -w3.y : w3.y;
    double2 o0; o0.x = y0x; o0.y = y0y;
    double2 o1; o1.x = y1x * w1.x - y1y * w1y; o1.y = y1x * w1y + y1y * w1.x;
    double2 o2; o2.x = y2x * w2.x - y2y * w2y; o2.y = y2x * w2y + y2y * w2.x;
    double2 o3; o3.x = y3x * w3.x - y3y * w3y; o3.y = y3x * w3y + y3y * w3.x;
    int ob = q + (4 * p) * L;
    A[SL(ob)]         = o0;
    A[SL(ob + L)]     = o1;
    A[SL(ob + 2 * L)] = o2;
    A[SL(ob + 3 * L)] = o3;
    __syncthreads();
  }
  double2 a0 = A[SL(t)];
  double2 a1 = A[SL(t + 256)];
  double2 b0 = A[SL(t + 128)];
  double2 b1 = A[SL(t + 384)];
  __syncthreads();
  double2 e0; e0.x = a0.x + a1.x; e0.y = a0.y + a1.y;
  double2 d0; d0.x = a0.x - a1.x; d0.y = a0.y - a1.y;
  double2 e1; e1.x = b0.x + b1.x; e1.y = b0.y + b1.y;
  double2 d1; d1.x = b0.x - b1.x; d1.y = b0.y - b1.y;
  A[SL(t)]       = e0;
  A[SL(t + 256)] = d0;
  A[SL(t + 128)] = e1;
  A[SL(t + 384)] = d1;
  __syncthreads();
}

__global__ __launch_bounds__(128) void k_istft(const float* __restrict__ mag, const float2* __restrict__ ang,
                                               float* __restrict__ frames,
                                               const double2* __restrict__ tw512,
                                               const double2* __restrict__ twh,
                                               const float* __restrict__ win)
{
  __shared__ double2 A[LDSN];
  int bf = blockIdx.x;          // b*512 + f
  int t = threadIdx.x;
  const float*  mrow = mag + bf * NFREQ;
  const float2* arow = ang + bf * NFREQ;
  for (int k = t; k < 512; k += 128) {
    float m1 = mrow[k];       float2 a1 = arow[k];
    int k2 = 512 - k;
    float m2 = mrow[k2];      float2 a2 = arow[k2];
    float S1x = __fmul_rn(m1, a1.x), S1y = __fmul_rn(m1, a1.y);
    float S2x = __fmul_rn(m2, a2.x), S2y = __fmul_rn(m2, a2.y);
    double2 Z;
    if (k == 0) {
      Z.x = 0.5 * ((double)S1x + (double)S2x);
      Z.y = 0.5 * ((double)S1x - (double)S2x);
    } else {
      double Xex = 0.5 * ((double)S1x + (double)S2x);
      double Xey = 0.5 * ((double)S1y - (double)S2y);
      double Dx  = 0.5 * ((double)S1x - (double)S2x);
      double Dy  = 0.5 * ((double)S1y + (double)S2y);
      double2 w = twh[k];
      double ux = w.x * Dx + w.y * Dy;
      double uy = w.x * Dy - w.y * Dx;
      Z.x = Xex - uy;
      Z.y = Xey + ux;
    }
    A[SL(k)] = Z;
  }
  __syncthreads();
  fft512d1<true>(A, tw512, t);
  float* frow = frames + bf * NFFT;
  for (int m = t; m < 512; m += 128) {
    double2 z = A[SL(m)];
    float xr = (float)(z.x * (1.0 / 512.0));
    float xi = (float)(z.y * (1.0 / 512.0));
    frow[2 * m]     = __fmul_rn(xr, win[2 * m]);
    frow[2 * m + 1] = __fmul_rn(xi, win[2 * m + 1]);
  }
}

// f32 OLA sample at wsq-coordinate j (identical formula since R6 -> bit-identical)
__device__ __forceinline__ float sig_sample(const float* __restrict__ fb, const float* __restrict__ wsq, int j)
{
  int gmax = j >> 8; if (gmax > NW - 1) gmax = NW - 1;
  int gmin = (j >= NFFT) ? ((j - (NFFT - 1) + 255) >> 8) : 0;
  float acc = 0.f;
  for (int g = gmin; g <= gmax; ++g)
    acc = __fadd_rn(acc, fb[g * NFFT + (j - (g << 8))]);
  float wv = wsq[j];
  return __fdiv_rn(acc, wv > 1e-11f ? wv : 1.0f);
}

// ---------------- FUSED iteration: on-the-fly OLA + stft + phase update + istft ----------------
// 2 frames per 128-thread block; each wave (64 lanes) owns one frame and a private LDS region.
// Reads frames from fsrc (previous iteration), writes new frames to fdst (double-buffered).
__global__ __launch_bounds__(128) void k_fused2(const float* __restrict__ fsrc,
                                                const float* __restrict__ wsq,
                                                const float* __restrict__ win,
                                                const double2* __restrict__ tw512,
                                                const double2* __restrict__ twh,
                                                const float* __restrict__ mag,
                                                float2* __restrict__ tprev,
                                                float* __restrict__ fdst)
{
  __shared__ double2 Abuf[2][LDSN];
  __shared__ float2 angBuf[2][NFREQ];
  int w = threadIdx.x >> 6;
  int l = threadIdx.x & 63;
  double2* A     = Abuf[w];
  float2*  angL  = angBuf[w];
  int bf = blockIdx.x * 2 + w;
  int b = bf >> 9;
  int f = bf & (NW - 1);
  const float* fb = fsrc + b * (NW * NFFT);

  // ---- pack: on-the-fly OLA + reflect + window, two reals per complex point ----
  for (int m = l; m < 512; m += 64) {
    float sv[2];
    #pragma unroll
    for (int r = 0; r < 2; ++r) {
      int tt = 2 * m + r;
      int n = f * HOP + tt - 512;        // signal coordinate, reflect-padded
      if (n < 0) n = -n;
      if (n >= SIGLEN) n = 2 * SIGLEN - 2 - n;
      float s = sig_sample(fb, wsq, n + 512);
      sv[r] = __fmul_rn(s, win[tt]);
    }
    double2 z; z.x = (double)sv[0]; z.y = (double)sv[1];
    A[SL(m)] = z;
  }
  wbar();
  fft512r8w<false>(A, tw512, l);

  // ---- unpack rfft bins + momentum phase update ----
  float2* prow = tprev + bf * NFREQ;
  const float cf = (float)(0.99 / 1.99);
  for (int k = l; k < NFREQ; k += 64) {
    double rx, ry;
    if (k == 0)        { rx = A[SL(0)].x + A[SL(0)].y; ry = 0.0; }
    else if (k == 512) { rx = A[SL(0)].x - A[SL(0)].y; ry = 0.0; }
    else {
      double2 Zk = A[SL(k)];
      double2 Zc = A[SL(512 - k)];
      double Xex = 0.5 * (Zk.x + Zc.x);
      double Xey = 0.5 * (Zk.y - Zc.y);
      double Gx  = 0.5 * (Zk.x - Zc.x);
      double Gy  = 0.5 * (Zk.y + Zc.y);
      double Xox = Gy, Xoy = -Gx;          // Xo = -i*G
      double2 tw = twh[k];
      rx = Xex + (tw.x * Xox - tw.y * Xoy);
      ry = Xey + (tw.x * Xoy + tw.y * Xox);
    }
    float rxf = (float)rx, ryf = (float)ry;  // rfft quantized to c64
    float2 pv = prow[k];
    float ax = __fsub_rn(rxf, __fmul_rn(pv.x, cf));
    float ay = __fsub_rn(ryf, __fmul_rn(pv.y, cf));
    double dx = (double)ax, dy = (double)ay;
    float d = (float)sqrt(dx * dx + dy * dy);   // np.abs(c64) = hypotf
    float d2 = __fadd_rn(d, 1e-16f);
    float inv = __fdiv_rn(1.0f, d2);
    angL[k] = make_float2(__fmul_rn(ax, inv), __fmul_rn(ay, inv));
    prow[k] = make_float2(rxf, ryf);
  }
  wbar();   // angL cross-lane reads next; same wave -> in-order DS

  // ---- repack: Hermitian pack mag*angL into A ----
  const float* mrow = mag + bf * NFREQ;
  for (int k = l; k < 512; k += 64) {
    float m1 = mrow[k];       float2 a1 = angL[k];
    int k2 = 512 - k;
    float m2 = mrow[k2];      float2 a2 = angL[k2];
    float S1x = __fmul_rn(m1, a1.x), S1y = __fmul_rn(m1, a1.y);
    float S2x = __fmul_rn(m2, a2.x), S2y = __fmul_rn(m2, a2.y);
    double2 Z;
    if (k == 0) {
      Z.x = 0.5 * ((double)S1x + (double)S2x);
      Z.y = 0.5 * ((double)S1x - (double)S2x);
    } else {
      double Xex = 0.5 * ((double)S1x + (double)S2x);
      double Xey = 0.5 * ((double)S1y - (double)S2y);
      double Dx  = 0.5 * ((double)S1x - (double)S2x);
      double Dy  = 0.5 * ((double)S1y + (double)S2y);
      double2 tw = twh[k];
      double ux = tw.x * Dx + tw.y * Dy;
      double uy = tw.x * Dy - tw.y * Dx;
      Z.x = Xex - uy;
      Z.y = Xey + ux;
    }
    A[SL(k)] = Z;
  }
  wbar();
  fft512r8w<true>(A, tw512, l);

  float* frow = fdst + bf * NFFT;
  for (int m = l; m < 512; m += 64) {
    double2 z = A[SL(m)];
    float xr = (float)(z.x * (1.0 / 512.0));
    float xi = (float)(z.y * (1.0 / 512.0));
    frow[2 * m]     = __fmul_rn(xr, win[2 * m]);
    frow[2 * m + 1] = __fmul_rn(xi, win[2 * m + 1]);
  }
}

// ---------------- final OLA -> audio f32 (pure streaming, no reduction) ----------------
__global__ __launch_bounds__(256) void k_ola(const float* __restrict__ frames, const float* __restrict__ wsq,
                                             float* __restrict__ audio)
{
  int idx = blockIdx.x * 256 + threadIdx.x;  // < BATCH*NSAMP
  int b  = idx >> 17;
  int nn = idx & (NSAMP - 1);
  float v = 0.f;
  if (nn < SIGLEN)
    v = sig_sample(frames + b * (NW * NFFT), wsq, nn + 512);
  audio[idx] = v;
}

// ---------------- per-batch |max|, two-stage ----------------
constexpr int MAXCHUNK = 64;

__global__ __launch_bounds__(256) void k_max1(const float* __restrict__ audio, float* __restrict__ partial)
{
  int blk = blockIdx.x;
  int b = blk / MAXCHUNK;
  int c = blk - b * MAXCHUNK;
  const float* arow = audio + b * NSAMP + c * (NSAMP / MAXCHUNK);
  float m = 0.f;
  for (int i = threadIdx.x; i < NSAMP / MAXCHUNK; i += 256)
    m = fmaxf(m, fabsf(arow[i]));
  __shared__ float red[256];
  red[threadIdx.x] = m;
  __syncthreads();
  for (int s = 128; s > 0; s >>= 1) {
    if (threadIdx.x < s) red[threadIdx.x] = fmaxf(red[threadIdx.x], red[threadIdx.x + s]);
    __syncthreads();
  }
  if (threadIdx.x == 0) partial[blk] = red[0];
}

__global__ __launch_bounds__(64) void k_max2(const float* __restrict__ partial, float* __restrict__ maxbuf)
{
  int b = blockIdx.x;
  __shared__ float red[64];
  red[threadIdx.x] = partial[b * MAXCHUNK + threadIdx.x];
  __syncthreads();
  for (int s = 32; s > 0; s >>= 1) {
    if (threadIdx.x < s) red[threadIdx.x] = fmaxf(red[threadIdx.x], red[threadIdx.x + s]);
    __syncthreads();
  }
  if (threadIdx.x == 0) maxbuf[b] = red[0];
}

__global__ __launch_bounds__(256) void k_norm(const float* __restrict__ audio, const float* __restrict__ maxbuf,
                                              float* __restrict__ out)
{
  int idx = blockIdx.x * 256 + threadIdx.x;
  int b = idx >> 17;
  float m = fmaxf(maxbuf[b], 1e-8f);
  out[idx] = __fmul_rn(__fdiv_rn(audio[idx], m), 0.9f);
}

extern "C" void kernel_launch(void* const* d_in, const int* in_sizes, int n_in,
                              void* d_out, int out_size, void* d_ws, size_t ws_size,
                              hipStream_t stream)
{
  const float* params = (const float*)d_in[0];
  float* out   = (float*)d_out;
  float* audio_out = out;                   // BATCH*NSAMP
  float* fs        = out + BATCH * NSAMP;   // BATCH*FH*FW (full_spec output)

  // workspace layout (16B-aligned first)
  double2* tw512  = (double2*)d_ws;                        // 512
  double2* twh    = tw512 + 512;                           // 512
  float2*  ang    = (float2*)(twh + 512);                  // NMAG c64 (initial phases only)
  float2*  tprev  = ang + NMAG;                            // NMAG c64
  float*   framesA= (float*)(tprev + NMAG);                // BATCH*NW*NFFT f32
  float*   framesB= framesA + BATCH * NW * NFFT;           // BATCH*NW*NFFT f32 (double buffer)
  float*   mag    = framesB + BATCH * NW * NFFT;           // NMAG f32
  float*   win    = mag + NMAG;                            // NFFT
  float*   wsq    = win + NFFT;                            // TOTAL_LEN
  float*   audio32= wsq + TOTAL_LEN;                       // BATCH*NSAMP
  float*   maxbuf = audio32 + BATCH * NSAMP;               // BATCH
  float*   partial= maxbuf + BATCH;                        // BATCH*MAXCHUNK

  k_init<<<512, 256, 0, stream>>>(win, tw512, twh, wsq, tprev);
  k_fullspec<<<(BATCH * FH * FW) / 256, 256, 0, stream>>>(params, fs);
  k_mag<<<(NMAG + 255) / 256, 256, 0, stream>>>(params, mag);
  k_phase<<<(NMAG + 255) / 256, 256, 0, stream>>>(ang);

  // istft0 with initial phases -> framesA, then 32x fused (ping-pong frames buffers)
  k_istft<<<BATCH * NW, 128, 0, stream>>>(mag, (const float2*)ang, framesA, tw512, twh, win);
  float* fsrc = framesA;
  float* fdst = framesB;
  for (int it = 0; it < NITER; ++it) {
    k_fused2<<<BATCH * NW / 2, 128, 0, stream>>>(fsrc, wsq, win, tw512, twh, mag, tprev, fdst);
    float* tmp = fsrc; fsrc = fdst; fdst = tmp;
  }
  // final frames are in fsrc after the last swap
  k_ola<<<(BATCH * NSAMP) / 256, 256, 0, stream>>>(fsrc, wsq, audio32);
  k_max1<<<BATCH * MAXCHUNK, 256, 0, stream>>>(audio32, partial);
  k_max2<<<BATCH, 64, 0, stream>>>(partial, maxbuf);
  k_norm<<<(BATCH * NSAMP) / 256, 256, 0, stream>>>(audio32, maxbuf, audio_out);
}

// Round 14
// 1303.692 us; speedup vs baseline: 1.6830x; 1.6830x over previous
//
#include <hip/hip_runtime.h>

typedef unsigned int u32;

constexpr int BATCH = 8;
constexpr int GH = 32, GW = 64;
constexpr int FH = 128, FW = 512;
constexpr int NFFT = 1024;
constexpr int HOP = 256;
constexpr int NFREQ = 513;
constexpr int NW = 512;                       // frames per batch
constexpr int SIGLEN = HOP * (NW - 1);        // 130816
constexpr int TOTAL_LEN = NFFT + HOP*(NW-1);  // 131840
constexpr int NITER = 32;
constexpr int NSAMP = 131072;
constexpr int NMAG = BATCH * NW * NFREQ;      // 2101248

// LDS index padding (9/8 stride)
#define SL(i) ((i) + ((i) >> 3))
constexpr int LDSN = 512 + 64;                // 576 slots

// ---------------- Threefry-2x32-20, partitionable path (key = (0,1)) ----------------
__device__ __forceinline__ void tf_round(u32 &x0, u32 &x1, int r) {
  x0 += x1;
  x1 = (x1 << r) | (x1 >> (32 - r));
  x1 ^= x0;
}

__device__ __forceinline__ void threefry2(u32 c0, u32 c1, u32 &o0, u32 &o1) {
  const u32 k0 = 0u, k1 = 1u;
  const u32 k2 = 0x1BD11BDAu ^ k0 ^ k1;
  u32 x0 = c0 + k0, x1 = c1 + k1;
  tf_round(x0, x1, 13); tf_round(x0, x1, 15); tf_round(x0, x1, 26); tf_round(x0, x1, 6);
  x0 += k1; x1 += k2 + 1u;
  tf_round(x0, x1, 17); tf_round(x0, x1, 29); tf_round(x0, x1, 16); tf_round(x0, x1, 24);
  x0 += k2; x1 += k0 + 2u;
  tf_round(x0, x1, 13); tf_round(x0, x1, 15); tf_round(x0, x1, 26); tf_round(x0, x1, 6);
  x0 += k0; x1 += k1 + 3u;
  tf_round(x0, x1, 17); tf_round(x0, x1, 29); tf_round(x0, x1, 16); tf_round(x0, x1, 24);
  x0 += k1; x1 += k2 + 4u;
  tf_round(x0, x1, 13); tf_round(x0, x1, 15); tf_round(x0, x1, 26); tf_round(x0, x1, 6);
  x0 += k2; x1 += k0 + 5u;
  o0 = x0; o1 = x1;
}

// ---------------- init: win f32, twiddle tables f64, wsq f32, tprev=0 ----------------
__global__ __launch_bounds__(256) void k_init(float* __restrict__ win,
                                              double2* __restrict__ tw512, double2* __restrict__ twh,
                                              float* __restrict__ wsq,
                                              float2* __restrict__ tprev)
{
  int idx = blockIdx.x * 256 + threadIdx.x;
  int stride = gridDim.x * 256;
  const double PI2 = 6.283185307179586476925286766559;
  for (int t = idx; t < NFFT; t += stride)
    win[t] = (float)(0.5 * (1.0 - cos(PI2 * (double)t / 1024.0)));  // _WIN f32
  for (int k = idx; k < 512; k += stride) {
    double th = -PI2 * (double)k / 512.0;
    double2 v; v.x = cos(th); v.y = sin(th);
    tw512[k] = v;                                     // e^{-2pi i k/512}
    double th2 = -PI2 * (double)k / 1024.0;
    double2 v2; v2.x = cos(th2); v2.y = sin(th2);
    twh[k] = v2;                                      // e^{-2pi i k/1024}
  }
  for (int j = idx; j < TOTAL_LEN; j += stride) {
    int gmax = j >> 8; if (gmax > NW - 1) gmax = NW - 1;
    int gmin = (j >= NFFT) ? ((j - (NFFT - 1) + 255) >> 8) : 0;
    float acc = 0.f;                       // f32 scatter-add, ascending frame order
    for (int g = gmin; g <= gmax; ++g) {
      float w = (float)(0.5 * (1.0 - cos(PI2 * (double)(j - (g << 8)) / 1024.0)));
      acc = __fadd_rn(acc, __fmul_rn(w, w));
    }
    wsq[j] = acc;
  }
  for (int i = idx; i < NMAG; i += stride)
    tprev[i] = make_float2(0.f, 0.f);
}

// ---------------- jax.image.resize bilinear, f32 weights WITH sum-normalization ----------------
__device__ __forceinline__ void lin_taps(float sf, int in, int &i0, int &i1, float &w0, float &w1)
{
  if (sf <= 0.0f)                  { i0 = 0;      i1 = 0;      w0 = 1.0f; w1 = 0.0f; return; }
  if (sf >= (float)(in - 1))       { i0 = in - 1; i1 = in - 1; w0 = 1.0f; w1 = 0.0f; return; }
  i0 = (int)sf; i1 = i0 + 1;
  float x0 = __fsub_rn(sf, (float)i0);   // exact
  float a0 = __fsub_rn(1.0f, x0);
  float S  = __fadd_rn(a0, x0);          // total_weight_sum = 1 +/- 2^-24
  w0 = __fdiv_rn(a0, S);                 // normalized (jax divides by the sum)
  w1 = __fdiv_rn(x0, S);
}

__device__ __forceinline__ float sf_H1(int H) {  // 32 -> 128
  return __fadd_rn(__fmul_rn(__fadd_rn((float)H, 0.5f), 0.25f), -0.5f);
}
__device__ __forceinline__ float sf_W1(int W) {  // 64 -> 512
  return __fadd_rn(__fmul_rn(__fadd_rn((float)W, 0.5f), 0.125f), -0.5f);
}
__device__ __forceinline__ float sf_H2(int K) {  // 128 -> 513, f32 inv_scale
  const float inv32 = (float)(1.0 / 4.0078125);  // f32(128/513)
  return __fadd_rn(__fmul_rn(__fadd_rn((float)K, 0.5f), inv32), -0.5f);
}

__device__ __forceinline__ float fs_at(const float* __restrict__ pb, int H, int W)
{
  int r0, r1; float u0, u1;
  lin_taps(sf_H1(H), GH, r0, r1, u0, u1);
  int c0, c1; float v0, v1;
  lin_taps(sf_W1(W), GW, c0, c1, v0, v1);
  float t0 = __fmaf_rn(u1, pb[r1 * GW + c0], __fmul_rn(u0, pb[r0 * GW + c0]));
  float t1 = __fmaf_rn(u1, pb[r1 * GW + c1], __fmul_rn(u0, pb[r0 * GW + c1]));
  return __fmaf_rn(v1, t1, __fmul_rn(v0, t0));
}

__global__ __launch_bounds__(256) void k_fullspec(const float* __restrict__ p, float* __restrict__ fs)
{
  int idx = blockIdx.x * 256 + threadIdx.x;
  if (idx >= BATCH * FH * FW) return;
  int b = idx >> 16;
  int h = (idx >> 9) & (FH - 1);
  int w = idx & (FW - 1);
  fs[idx] = fs_at(p + b * (GH * GW), h, w);
}

__global__ __launch_bounds__(256) void k_mag(const float* __restrict__ p, float* __restrict__ mag)
{
  int idx = blockIdx.x * 256 + threadIdx.x;
  if (idx >= NMAG) return;
  int b = idx / (NW * NFREQ);
  int rem = idx - b * (NW * NFREQ);
  int f = rem / NFREQ;
  int k = rem - f * NFREQ;
  const float* pb = p + b * (GH * GW);
  int h0, h1; float wa, wb;
  lin_taps(sf_H2(k), FH, h0, h1, wa, wb);
  float fs0 = fs_at(pb, h0, f);
  float fs1 = fs_at(pb, h1, f);
  float P0 = __fmul_rn(__fmul_rn(fs0, fs0), 100.0f);
  float P1 = __fmul_rn(__fmul_rn(fs1, fs1), 100.0f);
  float lin = __fmaf_rn(wb, P1, __fmul_rn(wa, P0));
  mag[idx] = __fsqrt_rn(fmaxf(lin, 0.0f));
}

__global__ __launch_bounds__(256) void k_phase(float2* __restrict__ ang)
{
  int idx = blockIdx.x * 256 + threadIdx.x;
  if (idx >= NMAG) return;
  int b = idx / (NW * NFREQ);
  int rem = idx - b * (NW * NFREQ);
  int f = rem / NFREQ;
  int k = rem - f * NFREQ;
  u32 cnt = (u32)(b * (NFREQ * NW) + k * NW + f);  // flat index in (B,513,512) C-order
  u32 w0, w1;
  threefry2(0u, cnt, w0, w1);
  u32 bits = w0 ^ w1;
  float u = __uint_as_float((bits >> 9) | 0x3f800000u) - 1.0f;
  float th = __fmul_rn((float)6.283185307179586, u);
  double thd = (double)th;
  ang[idx] = make_float2((float)cos(thd), (float)sin(thd));
}

// ---------------- 512-pt complex FFT: radix-4 Stockham, SINGLE LDS buffer, f64 ----------------
// 128 threads. ONE twiddle gather per butterfly; w2 = w1^2, w3 = w1*w2 in registers
// (<=1 ulp f64 perturbation vs table — absorbed by per-step f32 quantizers; proven class).
template<bool INV>
__device__ __forceinline__ void fft512d1(double2* __restrict__ A,
                                         const double2* __restrict__ tw512, int t)
{
  #pragma unroll
  for (int s = 0; s < 4; ++s) {
    const int L = 1 << (2 * s);
    const int m = 128 >> (2 * s);
    int p = t >> (2 * s);
    int q = t & (L - 1);
    double2 x0 = A[SL(q + (p)         * L)];
    double2 x1 = A[SL(q + (p + m)     * L)];
    double2 x2 = A[SL(q + (p + 2 * m) * L)];
    double2 x3 = A[SL(q + (p + 3 * m) * L)];
    __syncthreads();
    double t0x = x0.x + x2.x, t0y = x0.y + x2.y;
    double t1x = x0.x - x2.x, t1y = x0.y - x2.y;
    double t2x = x1.x + x3.x, t2y = x1.y + x3.y;
    double t3x = x1.x - x3.x, t3y = x1.y - x3.y;
    double y0x = t0x + t2x, y0y = t0y + t2y;
    double y2x = t0x - t2x, y2y = t0y - t2y;
    double y1x, y1y, y3x, y3y;
    if (INV) { y1x = t1x - t3y; y1y = t1y + t3x; y3x = t1x + t3y; y3y = t1y - t3x; }
    else     { y1x = t1x + t3y; y1y = t1y - t3x; y3x = t1x - t3y; y3y = t1y + t3x; }
    int base = p << (2 * s);
    double2 w1 = tw512[base];                 // single gather
    double w1y = INV ? -w1.y : w1.y;
    double w2x = w1.x * w1.x - w1y * w1y;     // w2 = w1^2 (conj commutes with powers)
    double w2y = 2.0 * w1.x * w1y;
    double w3x = w1.x * w2x - w1y * w2y;      // w3 = w1 * w2
    double w3y = w1.x * w2y + w1y * w2x;
    double2 o0; o0.x = y0x; o0.y = y0y;
    double2 o1; o1.x = y1x * w1.x - y1y * w1y; o1.y = y1x * w1y + y1y * w1.x;
    double2 o2; o2.x = y2x * w2x - y2y * w2y; o2.y = y2x * w2y + y2y * w2x;
    double2 o3; o3.x = y3x * w3x - y3y * w3y; o3.y = y3x * w3y + y3y * w3x;
    int ob = q + (4 * p) * L;
    A[SL(ob)]         = o0;
    A[SL(ob + L)]     = o1;
    A[SL(ob + 2 * L)] = o2;
    A[SL(ob + 3 * L)] = o3;
    __syncthreads();
  }
  double2 a0 = A[SL(t)];
  double2 a1 = A[SL(t + 256)];
  double2 b0 = A[SL(t + 128)];
  double2 b1 = A[SL(t + 384)];
  __syncthreads();
  double2 e0; e0.x = a0.x + a1.x; e0.y = a0.y + a1.y;
  double2 d0; d0.x = a0.x - a1.x; d0.y = a0.y - a1.y;
  double2 e1; e1.x = b0.x + b1.x; e1.y = b0.y + b1.y;
  double2 d1; d1.x = b0.x - b1.x; d1.y = b0.y - b1.y;
  A[SL(t)]       = e0;
  A[SL(t + 256)] = d0;
  A[SL(t + 128)] = e1;
  A[SL(t + 384)] = d1;
  __syncthreads();
}

// ---------------- initial ISTFT: irfft(1024) of mag*ang(global) via ifft(512), *win ----------------
__global__ __launch_bounds__(128) void k_istft(const float* __restrict__ mag, const float2* __restrict__ ang,
                                               float* __restrict__ frames,
                                               const double2* __restrict__ tw512,
                                               const double2* __restrict__ twh,
                                               const float* __restrict__ win)
{
  __shared__ double2 A[LDSN];
  int bf = blockIdx.x;          // b*512 + f
  int t = threadIdx.x;
  const float*  mrow = mag + bf * NFREQ;
  const float2* arow = ang + bf * NFREQ;
  for (int k = t; k < 512; k += 128) {
    float m1 = mrow[k];       float2 a1 = arow[k];
    int k2 = 512 - k;
    float m2 = mrow[k2];      float2 a2 = arow[k2];
    float S1x = __fmul_rn(m1, a1.x), S1y = __fmul_rn(m1, a1.y);
    float S2x = __fmul_rn(m2, a2.x), S2y = __fmul_rn(m2, a2.y);
    double2 Z;
    if (k == 0) {
      Z.x = 0.5 * ((double)S1x + (double)S2x);
      Z.y = 0.5 * ((double)S1x - (double)S2x);
    } else {
      double Xex = 0.5 * ((double)S1x + (double)S2x);
      double Xey = 0.5 * ((double)S1y - (double)S2y);
      double Dx  = 0.5 * ((double)S1x - (double)S2x);
      double Dy  = 0.5 * ((double)S1y + (double)S2y);
      double2 w = twh[k];                  // e^{-2pi i k/1024}
      double ux = w.x * Dx + w.y * Dy;     // conj(w)*D
      double uy = w.x * Dy - w.y * Dx;
      Z.x = Xex - uy;
      Z.y = Xey + ux;
    }
    A[SL(k)] = Z;
  }
  __syncthreads();
  fft512d1<true>(A, tw512, t);
  float* frow = frames + bf * NFFT;
  for (int m = t; m < 512; m += 128) {
    double2 z = A[SL(m)];
    float xr = (float)(z.x * (1.0 / 512.0));
    float xi = (float)(z.y * (1.0 / 512.0));
    frow[2 * m]     = __fmul_rn(xr, win[2 * m]);
    frow[2 * m + 1] = __fmul_rn(xi, win[2 * m + 1]);
  }
}

// f32 OLA sample at wsq-coordinate j
__device__ __forceinline__ float sig_sample(const float* __restrict__ fb, const float* __restrict__ wsq, int j)
{
  int gmax = j >> 8; if (gmax > NW - 1) gmax = NW - 1;
  int gmin = (j >= NFFT) ? ((j - (NFFT - 1) + 255) >> 8) : 0;
  float acc = 0.f;
  for (int g = gmin; g <= gmax; ++g)
    acc = __fadd_rn(acc, fb[g * NFFT + (j - (g << 8))]);
  float wv = wsq[j];
  return __fdiv_rn(acc, wv > 1e-11f ? wv : 1.0f);
}

// ---------------- per-iteration: OLA + reflect-pad -> xp[b][0..TOTAL_LEN) ----------------
__global__ __launch_bounds__(256) void k_sig(const float* __restrict__ frames, const float* __restrict__ wsq,
                                             float* __restrict__ xp)
{
  int idx = blockIdx.x * 256 + threadIdx.x;   // < BATCH*TOTAL_LEN
  int b = idx / TOTAL_LEN;
  int j = idx - b * TOTAL_LEN;
  int n = j - 512;
  if (n < 0) n = -n;
  if (n >= SIGLEN) n = 2 * SIGLEN - 2 - n;
  xp[idx] = sig_sample(frames + b * (NW * NFFT), wsq, n + 512);
}

// ---------------- FUSED: stft_it (+ phase update in LDS) + istft_{it+1} ----------------
__global__ __launch_bounds__(128) void k_fused(const float* __restrict__ xp,
                                               const float* __restrict__ win,
                                               const double2* __restrict__ tw512,
                                               const double2* __restrict__ twh,
                                               const float* __restrict__ mag,
                                               float2* __restrict__ tprev,
                                               float* __restrict__ frames)
{
  __shared__ double2 A[LDSN];
  __shared__ float2 angL[NFREQ];
  int bf = blockIdx.x;
  int b = bf >> 9;
  int f = bf & (NW - 1);
  int t = threadIdx.x;

  // ---- forward: pack two real samples per complex point ----
  const float* xrow = xp + b * TOTAL_LEN + f * HOP;
  for (int m = t; m < 512; m += 128) {
    float s0 = __fmul_rn(xrow[2 * m],     win[2 * m]);
    float s1 = __fmul_rn(xrow[2 * m + 1], win[2 * m + 1]);
    double2 z; z.x = (double)s0; z.y = (double)s1;
    A[SL(m)] = z;
  }
  __syncthreads();
  fft512d1<false>(A, tw512, t);     // result in A

  // ---- unpack rfft bins + momentum phase update (all f32 boundary ops) ----
  float2* prow = tprev + bf * NFREQ;
  const float cf = (float)(0.99 / 1.99);
  for (int k = t; k < NFREQ; k += 128) {
    double rx, ry;
    if (k == 0)        { rx = A[SL(0)].x + A[SL(0)].y; ry = 0.0; }
    else if (k == 512) { rx = A[SL(0)].x - A[SL(0)].y; ry = 0.0; }
    else {
      double2 Zk = A[SL(k)];
      double2 Zc = A[SL(512 - k)];
      double Xex = 0.5 * (Zk.x + Zc.x);
      double Xey = 0.5 * (Zk.y - Zc.y);
      double Gx  = 0.5 * (Zk.x - Zc.x);
      double Gy  = 0.5 * (Zk.y + Zc.y);
      double Xox = Gy, Xoy = -Gx;          // Xo = -i*G
      double2 w = twh[k];
      rx = Xex + (w.x * Xox - w.y * Xoy);  // S = Xe + w*Xo
      ry = Xey + (w.x * Xoy + w.y * Xox);
    }
    float rxf = (float)rx, ryf = (float)ry;  // rfft quantized to c64
    float2 pv = prow[k];
    float ax = __fsub_rn(rxf, __fmul_rn(pv.x, cf));
    float ay = __fsub_rn(ryf, __fmul_rn(pv.y, cf));
    double dx = (double)ax, dy = (double)ay;
    float d = (float)sqrt(dx * dx + dy * dy);   // np.abs(c64) = hypotf
    float d2 = __fadd_rn(d, 1e-16f);
    float inv = __fdiv_rn(1.0f, d2);
    angL[k] = make_float2(__fmul_rn(ax, inv), __fmul_rn(ay, inv));
    prow[k] = make_float2(rxf, ryf);
  }
  __syncthreads();   // angL complete; all reads of A (rfft) done before repack

  // ---- inverse: Hermitian pack mag*angL into A ----
  const float* mrow = mag + bf * NFREQ;
  for (int k = t; k < 512; k += 128) {
    float m1 = mrow[k];       float2 a1 = angL[k];
    int k2 = 512 - k;
    float m2 = mrow[k2];      float2 a2 = angL[k2];
    float S1x = __fmul_rn(m1, a1.x), S1y = __fmul_rn(m1, a1.y);
    float S2x = __fmul_rn(m2, a2.x), S2y = __fmul_rn(m2, a2.y);
    double2 Z;
    if (k == 0) {
      Z.x = 0.5 * ((double)S1x + (double)S2x);
      Z.y = 0.5 * ((double)S1x - (double)S2x);
    } else {
      double Xex = 0.5 * ((double)S1x + (double)S2x);
      double Xey = 0.5 * ((double)S1y - (double)S2y);
      double Dx  = 0.5 * ((double)S1x - (double)S2x);
      double Dy  = 0.5 * ((double)S1y + (double)S2y);
      double2 w = twh[k];
      double ux = w.x * Dx + w.y * Dy;
      double uy = w.x * Dy - w.y * Dx;
      Z.x = Xex - uy;
      Z.y = Xey + ux;
    }
    A[SL(k)] = Z;
  }
  __syncthreads();
  fft512d1<true>(A, tw512, t);
  float* frow = frames + bf * NFFT;
  for (int m = t; m < 512; m += 128) {
    double2 z = A[SL(m)];
    float xr = (float)(z.x * (1.0 / 512.0));
    float xi = (float)(z.y * (1.0 / 512.0));
    frow[2 * m]     = __fmul_rn(xr, win[2 * m]);
    frow[2 * m + 1] = __fmul_rn(xi, win[2 * m + 1]);
  }
}

// ---------------- final OLA -> audio f32 (pure streaming, no reduction) ----------------
__global__ __launch_bounds__(256) void k_ola(const float* __restrict__ frames, const float* __restrict__ wsq,
                                             float* __restrict__ audio)
{
  int idx = blockIdx.x * 256 + threadIdx.x;  // < BATCH*NSAMP
  int b  = idx >> 17;
  int nn = idx & (NSAMP - 1);
  float v = 0.f;
  if (nn < SIGLEN)
    v = sig_sample(frames + b * (NW * NFFT), wsq, nn + 512);
  audio[idx] = v;
}

// ---------------- per-batch |max|, two-stage ----------------
constexpr int MAXCHUNK = 64;

__global__ __launch_bounds__(256) void k_max1(const float* __restrict__ audio, float* __restrict__ partial)
{
  int blk = blockIdx.x;
  int b = blk / MAXCHUNK;
  int c = blk - b * MAXCHUNK;
  const float* arow = audio + b * NSAMP + c * (NSAMP / MAXCHUNK);
  float m = 0.f;
  for (int i = threadIdx.x; i < NSAMP / MAXCHUNK; i += 256)
    m = fmaxf(m, fabsf(arow[i]));
  __shared__ float red[256];
  red[threadIdx.x] = m;
  __syncthreads();
  for (int s = 128; s > 0; s >>= 1) {
    if (threadIdx.x < s) red[threadIdx.x] = fmaxf(red[threadIdx.x], red[threadIdx.x + s]);
    __syncthreads();
  }
  if (threadIdx.x == 0) partial[blk] = red[0];
}

__global__ __launch_bounds__(64) void k_max2(const float* __restrict__ partial, float* __restrict__ maxbuf)
{
  int b = blockIdx.x;
  __shared__ float red[64];
  red[threadIdx.x] = partial[b * MAXCHUNK + threadIdx.x];
  __syncthreads();
  for (int s = 32; s > 0; s >>= 1) {
    if (threadIdx.x < s) red[threadIdx.x] = fmaxf(red[threadIdx.x], red[threadIdx.x + s]);
    __syncthreads();
  }
  if (threadIdx.x == 0) maxbuf[b] = red[0];
}

__global__ __launch_bounds__(256) void k_norm(const float* __restrict__ audio, const float* __restrict__ maxbuf,
                                              float* __restrict__ out)
{
  int idx = blockIdx.x * 256 + threadIdx.x;
  int b = idx >> 17;
  float m = fmaxf(maxbuf[b], 1e-8f);
  out[idx] = __fmul_rn(__fdiv_rn(audio[idx], m), 0.9f);
}

extern "C" void kernel_launch(void* const* d_in, const int* in_sizes, int n_in,
                              void* d_out, int out_size, void* d_ws, size_t ws_size,
                              hipStream_t stream)
{
  const float* params = (const float*)d_in[0];
  float* out   = (float*)d_out;
  float* audio_out = out;                   // BATCH*NSAMP
  float* fs        = out + BATCH * NSAMP;   // BATCH*FH*FW (full_spec output)

  // workspace layout (16B-aligned first)
  double2* tw512  = (double2*)d_ws;                        // 512
  double2* twh    = tw512 + 512;                           // 512
  float2*  ang    = (float2*)(twh + 512);                  // NMAG c64 (initial phases only)
  float2*  tprev  = ang + NMAG;                            // NMAG c64
  float*   frames = (float*)(tprev + NMAG);                // BATCH*NW*NFFT f32
  float*   mag    = frames + BATCH * NW * NFFT;            // NMAG f32
  float*   xp     = mag + NMAG;                            // BATCH*TOTAL_LEN f32
  float*   win    = xp + BATCH * TOTAL_LEN;                // NFFT
  float*   wsq    = win + NFFT;                            // TOTAL_LEN
  float*   audio32= wsq + TOTAL_LEN;                       // BATCH*NSAMP
  float*   maxbuf = audio32 + BATCH * NSAMP;               // BATCH
  float*   partial= maxbuf + BATCH;                        // BATCH*MAXCHUNK

  k_init<<<512, 256, 0, stream>>>(win, tw512, twh, wsq, tprev);
  k_fullspec<<<(BATCH * FH * FW) / 256, 256, 0, stream>>>(params, fs);
  k_mag<<<(NMAG + 255) / 256, 256, 0, stream>>>(params, mag);
  k_phase<<<(NMAG + 255) / 256, 256, 0, stream>>>(ang);

  // istft0 with initial phases, then 32x [OLA->xp ; fused stft+update+istft]
  k_istft<<<BATCH * NW, 128, 0, stream>>>(mag, (const float2*)ang, frames, tw512, twh, win);
  for (int it = 0; it < NITER; ++it) {
    k_sig<<<(BATCH * TOTAL_LEN) / 256, 256, 0, stream>>>(frames, wsq, xp);
    k_fused<<<BATCH * NW, 128, 0, stream>>>(xp, win, tw512, twh, mag, tprev, frames);
  }
  k_ola<<<(BATCH * NSAMP) / 256, 256, 0, stream>>>(frames, wsq, audio32);
  k_max1<<<BATCH * MAXCHUNK, 256, 0, stream>>>(audio32, partial);
  k_max2<<<BATCH, 64, 0, stream>>>(partial, maxbuf);
  k_norm<<<(BATCH * NSAMP) / 256, 256, 0, stream>>>(audio32, maxbuf, audio_out);
}